// Round 1
// baseline (1377.085 us; speedup 1.0000x reference)
//
#include <hip/hip_runtime.h>

#define N_NODES 50000
#define N_EDGES 600000
#define D 128
#define TILE_N 32

// ---------------------------------------------------------------------------
// Kernel 1: S[dst[e]] += e_h[e]  (row-wise scatter-add, f32 atomics)
// One thread per (edge, 4-feature group) -> 32 threads/edge, float4 loads.
// ---------------------------------------------------------------------------
__global__ __launch_bounds__(256) void scatter_kernel(
    const float* __restrict__ e_h, const int* __restrict__ dst,
    float* __restrict__ S)
{
    long long idx = (long long)blockIdx.x * 256 + threadIdx.x;
    int edge = (int)(idx >> 5);
    if (edge >= N_EDGES) return;
    int f = ((int)idx & 31) << 2;

    const float4 v = *(const float4*)(e_h + (size_t)edge * D + f);
    float* p = S + (size_t)dst[edge] * D + f;
    atomicAdd(p + 0, v.x);
    atomicAdd(p + 1, v.y);
    atomicAdd(p + 2, v.z);
    atomicAdd(p + 3, v.w);
}

// ---------------------------------------------------------------------------
// Kernel 2: out[n] = ((h[n] .* S[n]) @ W^T + b) * norm[n]
// Tile: 32 nodes x 128 cols per block of 256 threads.
// Per thread: 4 nodes x 4 cols (cols strided by 32 for coalesced stores and
// conflict-free swizzled W reads).
// LDS: W swizzled 64 KB + A-tile 16 KB = 80 KB -> 2 blocks/CU.
// ---------------------------------------------------------------------------
__global__ __launch_bounds__(256, 2) void gemm_kernel(
    const float* __restrict__ h, const float* __restrict__ S,
    const float* __restrict__ norm, const float* __restrict__ W,
    const float* __restrict__ b, float* __restrict__ out)
{
    __shared__ float Wl[D * D];       // swizzled: row j, k-granule g stored at (g + j) & 31
    __shared__ float Al[TILE_N * D];  // A = h .* S, row-major

    const int tid = threadIdx.x;
    const int n0  = blockIdx.x * TILE_N;

    // ---- stage W (granule-swizzled to avoid stride-128 bank conflicts) ----
    // 16384 floats = 4096 float4 groups / 256 threads = 16 iters
    for (int it = 0; it < 16; ++it) {
        int group = it * 256 + tid;          // 0..4095
        int j   = group >> 5;                // row of W (output col)
        int kg  = group & 31;                // k-granule (k/4)
        float4 wv = *(const float4*)(W + (size_t)j * D + (kg << 2));
        int g = (kg + j) & 31;               // swizzled granule
        *(float4*)(Wl + j * D + (g << 2)) = wv;
    }

    // ---- stage A = h .* S ----
    // 4096 floats = 1024 float4 groups / 256 threads = 4 iters
    for (int it = 0; it < 4; ++it) {
        int group = it * 256 + tid;          // 0..1023
        int nl = group >> 5;
        int f  = (group & 31) << 2;
        int n  = n0 + nl;
        float4 a = make_float4(0.f, 0.f, 0.f, 0.f);
        if (n < N_NODES) {
            float4 hv = *(const float4*)(h + (size_t)n * D + f);
            float4 sv = *(const float4*)(S + (size_t)n * D + f);
            a = make_float4(hv.x * sv.x, hv.y * sv.y, hv.z * sv.z, hv.w * sv.w);
        }
        *(float4*)(Al + nl * D + f) = a;
    }

    __syncthreads();

    // ---- compute ----
    const int cg = tid & 31;   // col group: cols c = cg + 32*j
    const int ng = tid >> 5;   // node group: nodes nl = ng*4 + i

    float acc[4][4];
#pragma unroll
    for (int i = 0; i < 4; ++i)
#pragma unroll
        for (int j = 0; j < 4; ++j) acc[i][j] = 0.f;

#pragma unroll 4
    for (int kc = 0; kc < 32; ++kc) {        // k = kc*4 .. kc*4+3
        float4 a[4];
#pragma unroll
        for (int i = 0; i < 4; ++i)
            a[i] = *(const float4*)(Al + (ng * 4 + i) * D + (kc << 2));  // broadcast
        float4 w[4];
#pragma unroll
        for (int j = 0; j < 4; ++j) {
            int c = cg + 32 * j;
            int g = (kc + c) & 31;
            w[j] = *(const float4*)(Wl + c * D + (g << 2));
        }
#pragma unroll
        for (int i = 0; i < 4; ++i)
#pragma unroll
            for (int j = 0; j < 4; ++j)
                acc[i][j] += a[i].x * w[j].x + a[i].y * w[j].y +
                             a[i].z * w[j].z + a[i].w * w[j].w;
    }

    // ---- epilogue: +b, *norm, store ----
    float bias[4];
#pragma unroll
    for (int j = 0; j < 4; ++j) bias[j] = b[cg + 32 * j];

#pragma unroll
    for (int i = 0; i < 4; ++i) {
        int n = n0 + ng * 4 + i;
        if (n >= N_NODES) break;
        float nv = norm[n];
#pragma unroll
        for (int j = 0; j < 4; ++j) {
            out[(size_t)n * D + cg + 32 * j] = (acc[i][j] + bias[j]) * nv;
        }
    }
}

// ---------------------------------------------------------------------------
extern "C" void kernel_launch(void* const* d_in, const int* in_sizes, int n_in,
                              void* d_out, int out_size, void* d_ws, size_t ws_size,
                              hipStream_t stream) {
    const float* h    = (const float*)d_in[0];
    const float* e_h  = (const float*)d_in[1];
    const float* norm = (const float*)d_in[2];
    const int*   dst  = (const int*)d_in[3];
    const float* W    = (const float*)d_in[4];
    const float* b    = (const float*)d_in[5];
    float* out = (float*)d_out;

    const size_t s_bytes = (size_t)N_NODES * D * sizeof(float);  // 25.6 MB
    // S accumulator: workspace if big enough, else do it in-place in d_out
    // (safe: gemm_kernel block reads its S rows to LDS + __syncthreads before
    //  any thread of that block writes those same rows; blocks own disjoint rows)
    float* S = (ws_size >= s_bytes) ? (float*)d_ws : out;

    hipMemsetAsync(S, 0, s_bytes, stream);

    int scatter_blocks = (N_EDGES * 32 + 255) / 256;  // 75000
    scatter_kernel<<<scatter_blocks, 256, 0, stream>>>(e_h, dst, S);

    int gemm_blocks = (N_NODES + TILE_N - 1) / TILE_N;  // 1563
    gemm_kernel<<<gemm_blocks, 256, 0, stream>>>(h, S, norm, W, b, out);
}

// Round 2
// 654.066 us; speedup vs baseline: 2.1054x; 2.1054x over previous
//
#include <hip/hip_runtime.h>

#define N_NODES 50000
#define N_EDGES 600000
#define D 128
#define TILE_N 32

// ===========================================================================
// CSR-building path (no float atomics):
//   1) histogram: cnt[dst[e]]++          (int atomics, 600K ops)
//   2) scan: offsets = exclusive_scan(cnt); cursor = offsets copy
//   3) fill: edge_ids[atomicAdd(cursor[dst[e]])] = e
//   4) fused: per 32-node tile, A[n] = h[n] .* sum_{e in CSR[n]} e_h[e],
//             then out = (A @ W^T + b) * norm   (LDS GEMM)
// ===========================================================================

__global__ __launch_bounds__(256) void hist_kernel(
    const int* __restrict__ dst, int* __restrict__ cnt)
{
    int e = blockIdx.x * 256 + threadIdx.x;
    if (e < N_EDGES) atomicAdd(&cnt[dst[e]], 1);
}

// single block, 1024 threads; chunk-per-thread serial scan + block scan
__global__ __launch_bounds__(1024) void scan_kernel(
    const int* __restrict__ cnt, int* __restrict__ offsets,
    int* __restrict__ cursor)
{
    const int t = threadIdx.x;
    const int CHUNK = (N_NODES + 1023) / 1024;  // 49
    int lo = t * CHUNK;
    int hi = min(lo + CHUNK, N_NODES);

    int local = 0;
    for (int i = lo; i < hi; ++i) local += cnt[i];

    __shared__ int sdata[1024];
    sdata[t] = local;
    __syncthreads();
    // Hillis-Steele inclusive scan
    for (int s = 1; s < 1024; s <<= 1) {
        int v = (t >= s) ? sdata[t - s] : 0;
        __syncthreads();
        sdata[t] += v;
        __syncthreads();
    }
    int base = sdata[t] - local;  // exclusive prefix of this thread's chunk

    int run = base;
    for (int i = lo; i < hi; ++i) {
        offsets[i] = run;
        cursor[i]  = run;
        run += cnt[i];
    }
    if (t == 0) offsets[N_NODES] = N_EDGES;
}

__global__ __launch_bounds__(256) void fill_kernel(
    const int* __restrict__ dst, int* __restrict__ cursor,
    int* __restrict__ edge_ids)
{
    int e = blockIdx.x * 256 + threadIdx.x;
    if (e < N_EDGES) {
        int pos = atomicAdd(&cursor[dst[e]], 1);
        edge_ids[pos] = e;
    }
}

// ---------------------------------------------------------------------------
// Fused aggregate + GEMM.
// Phase 1: 32 teams x 8 threads; team = one node; thread owns 4 interleaved
//          float4 granules (lane8 + 8j) -> each load instr is 128B contiguous
//          per team. Accumulate sum of e_h rows in regs, multiply by h, -> LDS.
// Phase 2: 32x128 GEMM vs swizzled W in LDS (same as prior round).
// LDS: 64KB W + 16KB A = 80KB -> 2 blocks/CU.
// ---------------------------------------------------------------------------
__global__ __launch_bounds__(256, 2) void fused_kernel(
    const float* __restrict__ h, const float* __restrict__ e_h,
    const float* __restrict__ norm, const float* __restrict__ W,
    const float* __restrict__ b, const int* __restrict__ offsets,
    const int* __restrict__ edge_ids, float* __restrict__ out)
{
    __shared__ float Wl[D * D];       // swizzled: row c, granule g at (g + c) & 31
    __shared__ float Al[TILE_N * D];

    const int tid = threadIdx.x;
    const int n0  = blockIdx.x * TILE_N;

    // ---- stage W (granule-swizzled) ----
    for (int it = 0; it < 16; ++it) {
        int group = it * 256 + tid;          // 0..4095
        int c  = group >> 5;                 // W row (output col)
        int kg = group & 31;                 // k-granule
        float4 wv = *(const float4*)(W + (size_t)c * D + (kg << 2));
        int g = (kg + c) & 31;
        *(float4*)(Wl + c * D + (g << 2)) = wv;
    }

    // ---- phase 1: A = h .* sum(e_h over CSR edges) ----
    {
        const int team  = tid >> 3;   // node within tile
        const int lane8 = tid & 7;
        const int n = n0 + team;

        float4 acc[4];
#pragma unroll
        for (int j = 0; j < 4; ++j) acc[j] = make_float4(0.f, 0.f, 0.f, 0.f);

        if (n < N_NODES) {
            const int beg = offsets[n];
            const int end = offsets[n + 1];
            for (int i = beg; i < end; ++i) {
                const float* row = e_h + (size_t)edge_ids[i] * D;
#pragma unroll
                for (int j = 0; j < 4; ++j) {
                    float4 v = *(const float4*)(row + ((lane8 + 8 * j) << 2));
                    acc[j].x += v.x; acc[j].y += v.y;
                    acc[j].z += v.z; acc[j].w += v.w;
                }
            }
#pragma unroll
            for (int j = 0; j < 4; ++j) {
                float4 hv = *(const float4*)(h + (size_t)n * D + ((lane8 + 8 * j) << 2));
                acc[j].x *= hv.x; acc[j].y *= hv.y;
                acc[j].z *= hv.z; acc[j].w *= hv.w;
            }
        }
#pragma unroll
        for (int j = 0; j < 4; ++j)
            *(float4*)(Al + team * D + ((lane8 + 8 * j) << 2)) = acc[j];
    }

    __syncthreads();

    // ---- phase 2: GEMM ----
    const int cg = tid & 31;   // cols c = cg + 32*j
    const int ng = tid >> 5;   // nodes nl = ng*4 + i

    float facc[4][4];
#pragma unroll
    for (int i = 0; i < 4; ++i)
#pragma unroll
        for (int j = 0; j < 4; ++j) facc[i][j] = 0.f;

#pragma unroll 4
    for (int kc = 0; kc < 32; ++kc) {
        float4 a[4];
#pragma unroll
        for (int i = 0; i < 4; ++i)
            a[i] = *(const float4*)(Al + (ng * 4 + i) * D + (kc << 2));
        float4 w[4];
#pragma unroll
        for (int j = 0; j < 4; ++j) {
            int c = cg + 32 * j;
            int g = (kc + c) & 31;
            w[j] = *(const float4*)(Wl + c * D + (g << 2));
        }
#pragma unroll
        for (int i = 0; i < 4; ++i)
#pragma unroll
            for (int j = 0; j < 4; ++j)
                facc[i][j] += a[i].x * w[j].x + a[i].y * w[j].y +
                              a[i].z * w[j].z + a[i].w * w[j].w;
    }

    float bias[4];
#pragma unroll
    for (int j = 0; j < 4; ++j) bias[j] = b[cg + 32 * j];

#pragma unroll
    for (int i = 0; i < 4; ++i) {
        int n = n0 + ng * 4 + i;
        if (n >= N_NODES) break;
        float nv = norm[n];
#pragma unroll
        for (int j = 0; j < 4; ++j)
            out[(size_t)n * D + cg + 32 * j] = (facc[i][j] + bias[j]) * nv;
    }
}

// ===========================================================================
// Fallback path (ws too small): original float-atomic scatter + gemm
// ===========================================================================
__global__ __launch_bounds__(256) void scatter_kernel(
    const float* __restrict__ e_h, const int* __restrict__ dst,
    float* __restrict__ S)
{
    long long idx = (long long)blockIdx.x * 256 + threadIdx.x;
    int edge = (int)(idx >> 5);
    if (edge >= N_EDGES) return;
    int f = ((int)idx & 31) << 2;
    const float4 v = *(const float4*)(e_h + (size_t)edge * D + f);
    float* p = S + (size_t)dst[edge] * D + f;
    atomicAdd(p + 0, v.x);
    atomicAdd(p + 1, v.y);
    atomicAdd(p + 2, v.z);
    atomicAdd(p + 3, v.w);
}

__global__ __launch_bounds__(256, 2) void gemm_kernel(
    const float* __restrict__ h, const float* __restrict__ S,
    const float* __restrict__ norm, const float* __restrict__ W,
    const float* __restrict__ b, float* __restrict__ out)
{
    __shared__ float Wl[D * D];
    __shared__ float Al[TILE_N * D];
    const int tid = threadIdx.x;
    const int n0  = blockIdx.x * TILE_N;

    for (int it = 0; it < 16; ++it) {
        int group = it * 256 + tid;
        int c  = group >> 5;
        int kg = group & 31;
        float4 wv = *(const float4*)(W + (size_t)c * D + (kg << 2));
        int g = (kg + c) & 31;
        *(float4*)(Wl + c * D + (g << 2)) = wv;
    }
    for (int it = 0; it < 4; ++it) {
        int group = it * 256 + tid;
        int nl = group >> 5;
        int f  = (group & 31) << 2;
        int n  = n0 + nl;
        float4 a = make_float4(0.f, 0.f, 0.f, 0.f);
        if (n < N_NODES) {
            float4 hv = *(const float4*)(h + (size_t)n * D + f);
            float4 sv = *(const float4*)(S + (size_t)n * D + f);
            a = make_float4(hv.x * sv.x, hv.y * sv.y, hv.z * sv.z, hv.w * sv.w);
        }
        *(float4*)(Al + nl * D + f) = a;
    }
    __syncthreads();

    const int cg = tid & 31;
    const int ng = tid >> 5;
    float facc[4][4];
#pragma unroll
    for (int i = 0; i < 4; ++i)
#pragma unroll
        for (int j = 0; j < 4; ++j) facc[i][j] = 0.f;

#pragma unroll 4
    for (int kc = 0; kc < 32; ++kc) {
        float4 a[4];
#pragma unroll
        for (int i = 0; i < 4; ++i)
            a[i] = *(const float4*)(Al + (ng * 4 + i) * D + (kc << 2));
        float4 w[4];
#pragma unroll
        for (int j = 0; j < 4; ++j) {
            int c = cg + 32 * j;
            int g = (kc + c) & 31;
            w[j] = *(const float4*)(Wl + c * D + (g << 2));
        }
#pragma unroll
        for (int i = 0; i < 4; ++i)
#pragma unroll
            for (int j = 0; j < 4; ++j)
                facc[i][j] += a[i].x * w[j].x + a[i].y * w[j].y +
                              a[i].z * w[j].z + a[i].w * w[j].w;
    }
    float bias[4];
#pragma unroll
    for (int j = 0; j < 4; ++j) bias[j] = b[cg + 32 * j];
#pragma unroll
    for (int i = 0; i < 4; ++i) {
        int n = n0 + ng * 4 + i;
        if (n >= N_NODES) break;
        float nv = norm[n];
#pragma unroll
        for (int j = 0; j < 4; ++j)
            out[(size_t)n * D + cg + 32 * j] = (facc[i][j] + bias[j]) * nv;
    }
}

// ===========================================================================
extern "C" void kernel_launch(void* const* d_in, const int* in_sizes, int n_in,
                              void* d_out, int out_size, void* d_ws, size_t ws_size,
                              hipStream_t stream) {
    const float* h    = (const float*)d_in[0];
    const float* e_h  = (const float*)d_in[1];
    const float* norm = (const float*)d_in[2];
    const int*   dst  = (const int*)d_in[3];
    const float* W    = (const float*)d_in[4];
    const float* b    = (const float*)d_in[5];
    float* out = (float*)d_out;

    // ws layout (ints): cursor[N_NODES] | offsets[N_NODES+1] | edge_ids[N_EDGES]
    const size_t csr_bytes = ((size_t)N_NODES + (N_NODES + 1) + N_EDGES) * sizeof(int);

    if (ws_size >= csr_bytes) {
        int* cursor   = (int*)d_ws;
        int* offsets  = cursor + N_NODES;
        int* edge_ids = offsets + N_NODES + 1;

        hipMemsetAsync(cursor, 0, (size_t)N_NODES * sizeof(int), stream);

        int eblocks = (N_EDGES + 255) / 256;  // 2344
        hist_kernel<<<eblocks, 256, 0, stream>>>(dst, cursor);
        scan_kernel<<<1, 1024, 0, stream>>>(cursor, offsets, cursor);
        fill_kernel<<<eblocks, 256, 0, stream>>>(dst, cursor, edge_ids);

        int nblocks = (N_NODES + TILE_N - 1) / TILE_N;  // 1563
        fused_kernel<<<nblocks, 256, 0, stream>>>(h, e_h, norm, W, b,
                                                  offsets, edge_ids, out);
    } else {
        // fallback: float-atomic scatter into S (workspace or in-place in out)
        const size_t s_bytes = (size_t)N_NODES * D * sizeof(float);
        float* S = (ws_size >= s_bytes) ? (float*)d_ws : out;
        hipMemsetAsync(S, 0, s_bytes, stream);
        int scatter_blocks = (N_EDGES * 32 + 255) / 256;
        scatter_kernel<<<scatter_blocks, 256, 0, stream>>>(e_h, dst, S);
        int gemm_blocks = (N_NODES + TILE_N - 1) / TILE_N;
        gemm_kernel<<<gemm_blocks, 256, 0, stream>>>(h, S, norm, W, b, out);
    }
}

// Round 3
// 558.659 us; speedup vs baseline: 2.4650x; 1.1708x over previous
//
#include <hip/hip_runtime.h>

#define N_NODES 50000
#define N_EDGES 600000
#define D 128
#define TILE_N 32
#define SCAN_B 1024
#define N_SCAN_BLOCKS ((N_NODES + SCAN_B - 1) / SCAN_B)   // 49

// ===========================================================================
// Path: CSR build (int atomics only) -> high-occupancy gather-aggregate ->
//       LDS GEMM epilogue.
//   agg[n] = h[n] .* sum_{e: dst[e]=n} e_h[e]   (A, staged in ws)
//   out    = (A @ W^T + b) * norm
// ===========================================================================

__global__ __launch_bounds__(256) void hist_kernel(
    const int* __restrict__ dst, int* __restrict__ cnt)
{
    int e = blockIdx.x * 256 + threadIdx.x;
    if (e < N_EDGES) atomicAdd(&cnt[dst[e]], 1);
}

// --- hierarchical scan: per-block sums -> scan partials -> emit offsets ---
__global__ __launch_bounds__(SCAN_B) void scan_sum_kernel(
    const int* __restrict__ cnt, int* __restrict__ partial)
{
    int t = threadIdx.x;
    int i = blockIdx.x * SCAN_B + t;
    int v = (i < N_NODES) ? cnt[i] : 0;
#pragma unroll
    for (int s = 32; s > 0; s >>= 1) v += __shfl_down(v, s, 64);
    __shared__ int wsum[SCAN_B / 64];
    if ((t & 63) == 0) wsum[t >> 6] = v;
    __syncthreads();
    if (t < SCAN_B / 64) {
        int x = wsum[t];
#pragma unroll
        for (int s = SCAN_B / 128; s > 0; s >>= 1) x += __shfl_down(x, s, SCAN_B / 64);
        if (t == 0) partial[blockIdx.x] = x;
    }
}

__global__ __launch_bounds__(64) void scan_partial_kernel(int* __restrict__ partial)
{
    int t = threadIdx.x;
    int v = (t < N_SCAN_BLOCKS) ? partial[t] : 0;
    int own = v;
#pragma unroll
    for (int s = 1; s < 64; s <<= 1) {
        int u = __shfl_up(v, s, 64);
        if (t >= s) v += u;
    }
    if (t < N_SCAN_BLOCKS) partial[t] = v - own;   // exclusive prefix
}

__global__ __launch_bounds__(SCAN_B) void scan_emit_kernel(
    const int* __restrict__ cnt, const int* __restrict__ partial,
    int* __restrict__ offsets, int* __restrict__ cursor)
{
    int t = threadIdx.x;
    int i = blockIdx.x * SCAN_B + t;
    int v = (i < N_NODES) ? cnt[i] : 0;
    __shared__ int sd[SCAN_B];
    sd[t] = v;
    __syncthreads();
    for (int s = 1; s < SCAN_B; s <<= 1) {
        int u = (t >= s) ? sd[t - s] : 0;
        __syncthreads();
        sd[t] += u;
        __syncthreads();
    }
    int excl = sd[t] - v + partial[blockIdx.x];
    if (i < N_NODES) { offsets[i] = excl; cursor[i] = excl; }
    if (i == N_NODES - 1) offsets[N_NODES] = excl + v;   // == N_EDGES
}

__global__ __launch_bounds__(256) void fill_kernel(
    const int* __restrict__ dst, int* __restrict__ cursor,
    int* __restrict__ edge_ids)
{
    int e = blockIdx.x * 256 + threadIdx.x;
    if (e < N_EDGES) {
        int pos = atomicAdd(&cursor[dst[e]], 1);
        edge_ids[pos] = e;
    }
}

// ---------------------------------------------------------------------------
// Aggregate: A[n] = h[n] .* sum(e_h rows). 32 lanes/node, one float4/lane ->
// each row load instr is a full 512B contiguous segment per node. No LDS,
// tiny VGPR count -> 8 waves/SIMD to hide random-gather latency.
// Edge-id prefetch keeps one row-load in flight per id-load.
// ---------------------------------------------------------------------------
__global__ __launch_bounds__(256) void agg_kernel(
    const float* __restrict__ h, const float* __restrict__ e_h,
    const int* __restrict__ offsets, const int* __restrict__ edge_ids,
    float* __restrict__ A)
{
    int gid  = blockIdx.x * 256 + threadIdx.x;
    int node = gid >> 5;
    int lane = gid & 31;
    if (node >= N_NODES) return;

    const int beg = offsets[node];
    const int end = offsets[node + 1];

    float4 acc = make_float4(0.f, 0.f, 0.f, 0.f);
    int id = (beg < end) ? edge_ids[beg] : 0;
    for (int i = beg; i < end; ++i) {
        int nid = (i + 1 < end) ? edge_ids[i + 1] : 0;
        float4 v = *(const float4*)(e_h + (size_t)id * D + (lane << 2));
        acc.x += v.x; acc.y += v.y; acc.z += v.z; acc.w += v.w;
        id = nid;
    }
    float4 hv = *(const float4*)(h + (size_t)node * D + (lane << 2));
    acc.x *= hv.x; acc.y *= hv.y; acc.z *= hv.z; acc.w *= hv.w;
    *(float4*)(A + (size_t)node * D + (lane << 2)) = acc;
}

// ---------------------------------------------------------------------------
// GEMM: out = (A @ W^T + b) * norm.  32 nodes x 128 cols / block.
// W granule-swizzled in LDS (64KB) + A tile (16KB) -> 2 blocks/CU (compute
// phase; fine). Per thread 4 nodes x 4 cols.
// ---------------------------------------------------------------------------
__global__ __launch_bounds__(256, 2) void gemm_from_A(
    const float* __restrict__ A, const float* __restrict__ norm,
    const float* __restrict__ W, const float* __restrict__ b,
    float* __restrict__ out)
{
    __shared__ float Wl[D * D];
    __shared__ float Al[TILE_N * D];
    const int tid = threadIdx.x;
    const int n0  = blockIdx.x * TILE_N;

    for (int it = 0; it < 16; ++it) {
        int group = it * 256 + tid;
        int c  = group >> 5;
        int kg = group & 31;
        float4 wv = *(const float4*)(W + (size_t)c * D + (kg << 2));
        int g = (kg + c) & 31;
        *(float4*)(Wl + c * D + (g << 2)) = wv;
    }
    for (int it = 0; it < 4; ++it) {
        int group = it * 256 + tid;
        int nl = group >> 5;
        int f  = (group & 31) << 2;
        int n  = n0 + nl;
        float4 a = make_float4(0.f, 0.f, 0.f, 0.f);
        if (n < N_NODES) a = *(const float4*)(A + (size_t)n * D + f);
        *(float4*)(Al + nl * D + f) = a;
    }
    __syncthreads();

    const int cg = tid & 31;
    const int ng = tid >> 5;
    float facc[4][4];
#pragma unroll
    for (int i = 0; i < 4; ++i)
#pragma unroll
        for (int j = 0; j < 4; ++j) facc[i][j] = 0.f;

#pragma unroll 4
    for (int kc = 0; kc < 32; ++kc) {
        float4 a[4];
#pragma unroll
        for (int i = 0; i < 4; ++i)
            a[i] = *(const float4*)(Al + (ng * 4 + i) * D + (kc << 2));
        float4 w[4];
#pragma unroll
        for (int j = 0; j < 4; ++j) {
            int c = cg + 32 * j;
            int g = (kc + c) & 31;
            w[j] = *(const float4*)(Wl + c * D + (g << 2));
        }
#pragma unroll
        for (int i = 0; i < 4; ++i)
#pragma unroll
            for (int j = 0; j < 4; ++j)
                facc[i][j] += a[i].x * w[j].x + a[i].y * w[j].y +
                              a[i].z * w[j].z + a[i].w * w[j].w;
    }
    float bias[4];
#pragma unroll
    for (int j = 0; j < 4; ++j) bias[j] = b[cg + 32 * j];
#pragma unroll
    for (int i = 0; i < 4; ++i) {
        int n = n0 + ng * 4 + i;
        if (n >= N_NODES) break;
        float nv = norm[n];
#pragma unroll
        for (int j = 0; j < 4; ++j)
            out[(size_t)n * D + cg + 32 * j] = (facc[i][j] + bias[j]) * nv;
    }
}

// ===========================================================================
// Fallback (tiny ws): float-atomic scatter + fused gemm (round-1 style)
// ===========================================================================
__global__ __launch_bounds__(256) void scatter_kernel(
    const float* __restrict__ e_h, const int* __restrict__ dst,
    float* __restrict__ S)
{
    long long idx = (long long)blockIdx.x * 256 + threadIdx.x;
    int edge = (int)(idx >> 5);
    if (edge >= N_EDGES) return;
    int f = ((int)idx & 31) << 2;
    const float4 v = *(const float4*)(e_h + (size_t)edge * D + f);
    float* p = S + (size_t)dst[edge] * D + f;
    atomicAdd(p + 0, v.x);
    atomicAdd(p + 1, v.y);
    atomicAdd(p + 2, v.z);
    atomicAdd(p + 3, v.w);
}

__global__ __launch_bounds__(256, 2) void gemm_kernel(
    const float* __restrict__ h, const float* __restrict__ S,
    const float* __restrict__ norm, const float* __restrict__ W,
    const float* __restrict__ b, float* __restrict__ out)
{
    __shared__ float Wl[D * D];
    __shared__ float Al[TILE_N * D];
    const int tid = threadIdx.x;
    const int n0  = blockIdx.x * TILE_N;

    for (int it = 0; it < 16; ++it) {
        int group = it * 256 + tid;
        int c  = group >> 5;
        int kg = group & 31;
        float4 wv = *(const float4*)(W + (size_t)c * D + (kg << 2));
        int g = (kg + c) & 31;
        *(float4*)(Wl + c * D + (g << 2)) = wv;
    }
    for (int it = 0; it < 4; ++it) {
        int group = it * 256 + tid;
        int nl = group >> 5;
        int f  = (group & 31) << 2;
        int n  = n0 + nl;
        float4 a = make_float4(0.f, 0.f, 0.f, 0.f);
        if (n < N_NODES) {
            float4 hv = *(const float4*)(h + (size_t)n * D + f);
            float4 sv = *(const float4*)(S + (size_t)n * D + f);
            a = make_float4(hv.x * sv.x, hv.y * sv.y, hv.z * sv.z, hv.w * sv.w);
        }
        *(float4*)(Al + nl * D + f) = a;
    }
    __syncthreads();

    const int cg = tid & 31;
    const int ng = tid >> 5;
    float facc[4][4];
#pragma unroll
    for (int i = 0; i < 4; ++i)
#pragma unroll
        for (int j = 0; j < 4; ++j) facc[i][j] = 0.f;

#pragma unroll 4
    for (int kc = 0; kc < 32; ++kc) {
        float4 a[4];
#pragma unroll
        for (int i = 0; i < 4; ++i)
            a[i] = *(const float4*)(Al + (ng * 4 + i) * D + (kc << 2));
        float4 w[4];
#pragma unroll
        for (int j = 0; j < 4; ++j) {
            int c = cg + 32 * j;
            int g = (kc + c) & 31;
            w[j] = *(const float4*)(Wl + c * D + (g << 2));
        }
#pragma unroll
        for (int i = 0; i < 4; ++i)
#pragma unroll
            for (int j = 0; j < 4; ++j)
                facc[i][j] += a[i].x * w[j].x + a[i].y * w[j].y +
                              a[i].z * w[j].z + a[i].w * w[j].w;
    }
    float bias[4];
#pragma unroll
    for (int j = 0; j < 4; ++j) bias[j] = b[cg + 32 * j];
#pragma unroll
    for (int i = 0; i < 4; ++i) {
        int n = n0 + ng * 4 + i;
        if (n >= N_NODES) break;
        float nv = norm[n];
#pragma unroll
        for (int j = 0; j < 4; ++j)
            out[(size_t)n * D + cg + 32 * j] = (facc[i][j] + bias[j]) * nv;
    }
}

// ===========================================================================
extern "C" void kernel_launch(void* const* d_in, const int* in_sizes, int n_in,
                              void* d_out, int out_size, void* d_ws, size_t ws_size,
                              hipStream_t stream) {
    const float* h    = (const float*)d_in[0];
    const float* e_h  = (const float*)d_in[1];
    const float* norm = (const float*)d_in[2];
    const int*   dst  = (const int*)d_in[3];
    const float* W    = (const float*)d_in[4];
    const float* b    = (const float*)d_in[5];
    float* out = (float*)d_out;

    // ws layout: cursor[N] | offsets[N+1] | edge_ids[E] | partial[64] | A[N*D]
    const size_t ints_needed = (size_t)N_NODES + (N_NODES + 1) + N_EDGES + 64;
    const size_t full_bytes  = ints_needed * sizeof(int) + (size_t)N_NODES * D * sizeof(float);

    if (ws_size >= full_bytes) {
        int* cursor   = (int*)d_ws;
        int* offsets  = cursor + N_NODES;
        int* edge_ids = offsets + N_NODES + 1;
        int* partial  = edge_ids + N_EDGES;
        float* A      = (float*)(partial + 64);

        hipMemsetAsync(cursor, 0, (size_t)N_NODES * sizeof(int), stream);

        int eblocks = (N_EDGES + 255) / 256;
        hist_kernel<<<eblocks, 256, 0, stream>>>(dst, cursor);
        scan_sum_kernel<<<N_SCAN_BLOCKS, SCAN_B, 0, stream>>>(cursor, partial);
        scan_partial_kernel<<<1, 64, 0, stream>>>(partial);
        scan_emit_kernel<<<N_SCAN_BLOCKS, SCAN_B, 0, stream>>>(cursor, partial,
                                                               offsets, cursor);
        fill_kernel<<<eblocks, 256, 0, stream>>>(dst, cursor, edge_ids);

        int ablocks = ((N_NODES * 32) + 255) / 256;   // 6250
        agg_kernel<<<ablocks, 256, 0, stream>>>(h, e_h, offsets, edge_ids, A);

        int gblocks = (N_NODES + TILE_N - 1) / TILE_N;  // 1563
        gemm_from_A<<<gblocks, 256, 0, stream>>>(A, norm, W, b, out);
    } else {
        const size_t s_bytes = (size_t)N_NODES * D * sizeof(float);
        float* S = (ws_size >= s_bytes) ? (float*)d_ws : out;
        hipMemsetAsync(S, 0, s_bytes, stream);
        int scatter_blocks = (N_EDGES * 32 + 255) / 256;
        scatter_kernel<<<scatter_blocks, 256, 0, stream>>>(e_h, dst, S);
        int gemm_blocks = (N_NODES + TILE_N - 1) / TILE_N;
        gemm_kernel<<<gemm_blocks, 256, 0, stream>>>(h, S, norm, W, b, out);
    }
}